// Round 2
// baseline (312.708 us; speedup 1.0000x reference)
//
#include <hip/hip_runtime.h>
#include <hip/hip_fp16.h>
#include <stdint.h>

#define Bn 32
#define Cc 64
#define Hh 112
#define Ww 112
#define HWp (Hh*Ww)            // 12544
#define NPIX (Bn*HWp)          // 401408
#define PW 114                 // padded width
#define PHW (PW*PW)            // 12996 padded cells per image
#define ALPHA 0.25f

// workspace layout (bytes)
#define WB1_OFF   0                      // uint64[64*9]
#define WB2_OFF   4608
#define ASC1_OFF  9216                   // float[64]  (= ALPHA * mean|w|)
#define ASC2_OFF  9472
#define CI1_OFF   9728                   // int[64*9]  cint[o*9+type]
#define CI2_OFF   12032
#define BITS1_OFF 16384                  // uint64[Bn*PHW] = 3,326,976 B (padded, halo=0)
#define BITS2_OFF (16384 + 3326976)      // uint64[Bn*PHW]
#define OUT1H_OFF (16384 + 2*3326976)    // __half[NPIX*Cc] = 51,380,224 B (fp16 path)
#define WS_NEED   (OUT1H_OFF + (size_t)NPIX*Cc*2)

// Keep a register live at this point: forces the producing load to complete
// here instead of being sunk to the (much later) use.  (skill rule #17)
#define PIN(v) asm volatile("" : "+v"(v))

// 128 blocks x 64 lanes; block b<64 -> conv1 tables (o=b), else conv2.
__global__ __launch_bounds__(64) void prep_weights(
        const float* __restrict__ w3, const float* __restrict__ wpw,
        uint64_t* __restrict__ wb1, uint64_t* __restrict__ wb2,
        float* __restrict__ asc1, float* __restrict__ asc2,
        int* __restrict__ ci1, int* __restrict__ ci2) {
    int b = blockIdx.x;
    int lane = threadIdx.x;
    const float* w  = (b < 64) ? w3   : wpw;
    uint64_t* wbits = (b < 64) ? wb1  : wb2;
    float*    ascp  = (b < 64) ? asc1 : asc2;
    int*      cip   = (b < 64) ? ci1  : ci2;
    int o = b & 63;
    const float* wp = w + ((size_t)o * Cc + lane) * 9;
    float v[9]; float asum = 0.f;
    #pragma unroll
    for (int t = 0; t < 9; ++t) { v[t] = wp[t]; asum += fabsf(v[t]); }
    uint64_t bal[9];
    #pragma unroll
    for (int t = 0; t < 9; ++t) bal[t] = __ballot(v[t] < 0.f);
    if (lane < 9) {
        wbits[o * 9 + lane] = bal[lane];
        int ty = lane, tr = ty / 3, tc = ty % 3;
        int sum = 0;
        #pragma unroll
        for (int t = 0; t < 9; ++t) {
            int r = t / 3, c = t % 3;
            bool inv = (tr == 0 && r == 0) || (tr == 2 && r == 2) ||
                       (tc == 0 && c == 0) || (tc == 2 && c == 2);
            if (inv) sum += 64 - 2 * (int)__popcll(bal[t]);
        }
        cip[o * 9 + ty] = 576 - sum;
    }
    #pragma unroll
    for (int off = 32; off > 0; off >>= 1) asum += __shfl_down(asum, off, 64);
    if (lane == 0) ascp[o] = ALPHA * asum * (1.f / 576.f);
}

// One thread per PADDED cell; halo cells zero bits1+bits2; interior packs signs.
// All 64 channel loads issued up-front and pinned -> 64-deep MLP per thread.
__global__ __launch_bounds__(256, 4) void pack1(const float* __restrict__ x,
                                                const float* __restrict__ b11,
                                                uint64_t* __restrict__ bits1,
                                                uint64_t* __restrict__ bits2) {
    int pc = blockIdx.x * 256 + threadIdx.x;
    if (pc >= PHW) return;
    int n = blockIdx.y;
    int ph = pc / PW, pw = pc - ph * PW;
    size_t bi = (size_t)n * PHW + pc;
    if (ph == 0 || ph == PW - 1 || pw == 0 || pw == PW - 1) {
        bits1[bi] = 0; bits2[bi] = 0;
        return;
    }
    int hw = (ph - 1) * Ww + (pw - 1);
    const float* xp = x + (size_t)n * Cc * HWp + hw;
    float v[Cc];
    #pragma unroll
    for (int j = 0; j < Cc; ++j) v[j] = xp[(size_t)j * HWp];
    #pragma unroll
    for (int j = 0; j < Cc; ++j) PIN(v[j]);
    uint64_t m = 0;
    #pragma unroll
    for (int j = 0; j < Cc; ++j)
        if (v[j] + b11[j] < 0.f) m |= (1ull << j);
    bits1[bi] = m;
}

// conv1 + residual(x) + b12/prelu(a1)/b13 -> out1 (OutT); pack bits2=(out1+b21<0).
// Structure: load 9 window words, preload+pin ALL 64 x values, then a fully
// unrolled straight-line pass over the 64 output channels (weights/biases are
// wave-uniform -> s_load; lci is [t9][o] so per-o LDS reads use imm offsets).
template <typename OutT>
__global__ __launch_bounds__(256, 4) void conv1_ep(
        const float* __restrict__ x, const uint64_t* __restrict__ bits1,
        const uint64_t* __restrict__ wb, const float* __restrict__ asc,
        const int* __restrict__ cint,
        const float* __restrict__ b12, const float* __restrict__ a1,
        const float* __restrict__ b13, const float* __restrict__ b21,
        OutT* __restrict__ out1, uint64_t* __restrict__ bits2) {
    __shared__ int lci[10 * Cc];               // [t9][o]
    for (int i = threadIdx.x; i < Cc * 9; i += 256) {
        int o = i / 9, ty = i - o * 9;
        lci[ty * Cc + o] = cint[i];
    }
    __syncthreads();

    int hw = blockIdx.x * 256 + threadIdx.x;     // 49*256 = 12544 exact
    int n = blockIdx.y;
    int h = hw / Ww, w = hw - h * Ww;
    int t9 = ((h == 0) ? 0 : (h == Hh - 1) ? 6 : 3) +
             ((w == 0) ? 0 : (w == Ww - 1) ? 2 : 1);
    const int* lcit = lci + t9 * Cc;             // per-o access: imm offset o*4

    const uint64_t* bp = bits1 + (size_t)n * PHW + (h + 1) * PW + (w + 1);
    uint64_t w00 = bp[-PW - 1], w01 = bp[-PW], w02 = bp[-PW + 1];
    uint64_t w10 = bp[-1],      w11 = bp[0],   w12 = bp[1];
    uint64_t w20 = bp[PW - 1],  w21 = bp[PW],  w22 = bp[PW + 1];

    const float* xp = x + (size_t)n * Cc * HWp + hw;
    OutT* op = out1 + (size_t)n * Cc * HWp + hw;

    float xv[Cc];
    #pragma unroll
    for (int j = 0; j < Cc; ++j) xv[j] = xp[(size_t)j * HWp];
    #pragma unroll
    for (int j = 0; j < Cc; ++j) PIN(xv[j]);

    uint64_t m2 = 0;
    #pragma unroll
    for (int o = 0; o < Cc; ++o) {
        const uint64_t* wo = wb + o * 9;
        int s;
        s  = (int)__popcll(w00 ^ wo[0]);
        s += (int)__popcll(w01 ^ wo[1]);
        s += (int)__popcll(w02 ^ wo[2]);
        s += (int)__popcll(w10 ^ wo[3]);
        s += (int)__popcll(w11 ^ wo[4]);
        s += (int)__popcll(w12 ^ wo[5]);
        s += (int)__popcll(w20 ^ wo[6]);
        s += (int)__popcll(w21 ^ wo[7]);
        s += (int)__popcll(w22 ^ wo[8]);
        int m = lcit[o] - (s << 1);
        float v = fmaf(asc[o], (float)m, xv[o]);
        v += b12[o];
        v = v >= 0.f ? v : a1[o] * v;
        v += b13[o];
        op[(size_t)o * HWp] = (OutT)v;
        if (v + b21[o] < 0.f) m2 |= (1ull << o);
    }
    bits2[(size_t)n * PHW + (h + 1) * PW + (w + 1)] = m2;
}

// conv2 + residual(out1) + b22/prelu(a2)/b23 -> out (fp32); same structure.
template <typename InT>
__global__ __launch_bounds__(256, 4) void conv2_ep(
        const uint64_t* __restrict__ bits2, const InT* __restrict__ out1,
        const uint64_t* __restrict__ wb, const float* __restrict__ asc,
        const int* __restrict__ cint,
        const float* __restrict__ b22, const float* __restrict__ a2,
        const float* __restrict__ b23, float* __restrict__ out) {
    __shared__ int lci[10 * Cc];               // [t9][o]
    for (int i = threadIdx.x; i < Cc * 9; i += 256) {
        int o = i / 9, ty = i - o * 9;
        lci[ty * Cc + o] = cint[i];
    }
    __syncthreads();

    int hw = blockIdx.x * 256 + threadIdx.x;
    int n = blockIdx.y;
    int h = hw / Ww, w = hw - h * Ww;
    int t9 = ((h == 0) ? 0 : (h == Hh - 1) ? 6 : 3) +
             ((w == 0) ? 0 : (w == Ww - 1) ? 2 : 1);
    const int* lcit = lci + t9 * Cc;

    const uint64_t* bp = bits2 + (size_t)n * PHW + (h + 1) * PW + (w + 1);
    uint64_t w00 = bp[-PW - 1], w01 = bp[-PW], w02 = bp[-PW + 1];
    uint64_t w10 = bp[-1],      w11 = bp[0],   w12 = bp[1];
    uint64_t w20 = bp[PW - 1],  w21 = bp[PW],  w22 = bp[PW + 1];

    const InT* ip = out1 + (size_t)n * Cc * HWp + hw;
    float* op = out + (size_t)n * Cc * HWp + hw;

    float rv[Cc];
    #pragma unroll
    for (int j = 0; j < Cc; ++j) rv[j] = (float)ip[(size_t)j * HWp];
    #pragma unroll
    for (int j = 0; j < Cc; ++j) PIN(rv[j]);

    #pragma unroll
    for (int o = 0; o < Cc; ++o) {
        const uint64_t* wo = wb + o * 9;
        int s;
        s  = (int)__popcll(w00 ^ wo[0]);
        s += (int)__popcll(w01 ^ wo[1]);
        s += (int)__popcll(w02 ^ wo[2]);
        s += (int)__popcll(w10 ^ wo[3]);
        s += (int)__popcll(w11 ^ wo[4]);
        s += (int)__popcll(w12 ^ wo[5]);
        s += (int)__popcll(w20 ^ wo[6]);
        s += (int)__popcll(w21 ^ wo[7]);
        s += (int)__popcll(w22 ^ wo[8]);
        int m = lcit[o] - (s << 1);
        float v = fmaf(asc[o], (float)m, rv[o]);
        v += b22[o];
        v = v >= 0.f ? v : a2[o] * v;
        v += b23[o];
        op[(size_t)o * HWp] = v;
    }
}

extern "C" void kernel_launch(void* const* d_in, const int* in_sizes, int n_in,
                              void* d_out, int out_size, void* d_ws, size_t ws_size,
                              hipStream_t stream) {
    const float* x    = (const float*)d_in[0];
    const float* w3   = (const float*)d_in[1];
    const float* wpw  = (const float*)d_in[2];
    const float* b11  = (const float*)d_in[3];
    const float* b12  = (const float*)d_in[4];
    const float* b13  = (const float*)d_in[5];
    const float* b21  = (const float*)d_in[6];
    const float* b22  = (const float*)d_in[7];
    const float* b23  = (const float*)d_in[8];
    const float* a1   = (const float*)d_in[9];
    const float* a2   = (const float*)d_in[10];

    char* ws = (char*)d_ws;
    uint64_t* wb1   = (uint64_t*)(ws + WB1_OFF);
    uint64_t* wb2   = (uint64_t*)(ws + WB2_OFF);
    float*    asc1  = (float*)(ws + ASC1_OFF);
    float*    asc2  = (float*)(ws + ASC2_OFF);
    int*      ci1   = (int*)(ws + CI1_OFF);
    int*      ci2   = (int*)(ws + CI2_OFF);
    uint64_t* bits1 = (uint64_t*)(ws + BITS1_OFF);
    uint64_t* bits2 = (uint64_t*)(ws + BITS2_OFF);
    float*    out   = (float*)d_out;

    dim3 pgrid((PHW + 255) / 256, Bn);   // 51 x 32
    dim3 cgrid(HWp / 256, Bn);           // 49 x 32

    prep_weights<<<128, 64, 0, stream>>>(w3, wpw, wb1, wb2, asc1, asc2, ci1, ci2);
    pack1<<<pgrid, 256, 0, stream>>>(x, b11, bits1, bits2);

    if (ws_size >= WS_NEED) {
        __half* out1h = (__half*)(ws + OUT1H_OFF);
        conv1_ep<__half><<<cgrid, 256, 0, stream>>>(x, bits1, wb1, asc1, ci1,
                                                    b12, a1, b13, b21, out1h, bits2);
        conv2_ep<__half><<<cgrid, 256, 0, stream>>>(bits2, out1h, wb2, asc2, ci2,
                                                    b22, a2, b23, out);
    } else {
        conv1_ep<float><<<cgrid, 256, 0, stream>>>(x, bits1, wb1, asc1, ci1,
                                                   b12, a1, b13, b21, out, bits2);
        conv2_ep<float><<<cgrid, 256, 0, stream>>>(bits2, out, wb2, asc2, ci2,
                                                   b22, a2, b23, out);
    }
}

// Round 3
// 294.663 us; speedup vs baseline: 1.0612x; 1.0612x over previous
//
#include <hip/hip_runtime.h>
#include <hip/hip_fp16.h>
#include <stdint.h>

#define Bn 32
#define Cc 64
#define Hh 112
#define Ww 112
#define HWp (Hh*Ww)            // 12544
#define NPIX (Bn*HWp)          // 401408
#define PW 114                 // padded width
#define PHW (PW*PW)            // 12996 padded cells per image
#define NPAIR (HWp/2)          // 6272 pixel-pairs per image
#define WROW (Ww/2)            // 56 pairs per row
#define ALPHA 0.25f

typedef float    f32x2 __attribute__((ext_vector_type(2)));
typedef _Float16 f16x2 __attribute__((ext_vector_type(2)));

// workspace layout (bytes)
#define WB1_OFF   0                      // uint64[64*9]
#define WB2_OFF   4608
#define ASC1_OFF  9216                   // float[64]  (= ALPHA * mean|w|)
#define ASC2_OFF  9472
#define CI1_OFF   9728                   // int[64*10] (padded stride 10)
#define CI2_OFF   12288                  // int[64*10]
#define BITS1_OFF 16384                  // uint64[Bn*PHW] (padded, halo=0)
#define BITS2_OFF (16384 + 3326976)
#define OUT1H_OFF (16384 + 2*3326976)    // __half[NPIX*Cc] (fp16 path)
#define WS_NEED   (OUT1H_OFF + (size_t)NPIX*Cc*2)

// Compiler memory barrier: loads issued before it cannot sink past it,
// so a prefetch batch is guaranteed in flight under the following compute.
// (Register pins alone do NOT stop load reordering — R2 lesson.)
#define MEMFENCE() asm volatile("" ::: "memory")

// 128 blocks x 64 lanes; block b<64 -> conv1 tables (o=b), else conv2.
__global__ __launch_bounds__(64) void prep_weights(
        const float* __restrict__ w3, const float* __restrict__ wpw,
        uint64_t* __restrict__ wb1, uint64_t* __restrict__ wb2,
        float* __restrict__ asc1, float* __restrict__ asc2,
        int* __restrict__ ci1, int* __restrict__ ci2) {
    int b = blockIdx.x;
    int lane = threadIdx.x;
    const float* w  = (b < 64) ? w3   : wpw;
    uint64_t* wbits = (b < 64) ? wb1  : wb2;
    float*    ascp  = (b < 64) ? asc1 : asc2;
    int*      cip   = (b < 64) ? ci1  : ci2;
    int o = b & 63;
    const float* wp = w + ((size_t)o * Cc + lane) * 9;
    float v[9]; float asum = 0.f;
    #pragma unroll
    for (int t = 0; t < 9; ++t) { v[t] = wp[t]; asum += fabsf(v[t]); }
    uint64_t bal[9];
    #pragma unroll
    for (int t = 0; t < 9; ++t) bal[t] = __ballot(v[t] < 0.f);
    if (lane < 9) {
        wbits[o * 9 + lane] = bal[lane];
        int ty = lane, tr = ty / 3, tc = ty % 3;
        int sum = 0;
        #pragma unroll
        for (int t = 0; t < 9; ++t) {
            int r = t / 3, c = t % 3;
            bool inv = (tr == 0 && r == 0) || (tr == 2 && r == 2) ||
                       (tc == 0 && c == 0) || (tc == 2 && c == 2);
            if (inv) sum += 64 - 2 * (int)__popcll(bal[t]);
        }
        cip[o * 10 + ty] = 576 - sum;       // padded stride 10
    }
    #pragma unroll
    for (int off = 32; off > 0; off >>= 1) asum += __shfl_down(asum, off, 64);
    if (lane == 0) ascp[o] = ALPHA * asum * (1.f / 576.f);
}

// One thread per interior pixel-PAIR (f32x2 loads); blocks 25,26 zero the halo.
__global__ __launch_bounds__(256, 4) void pack1(const float* __restrict__ x,
                                                const float* __restrict__ b11,
                                                uint64_t* __restrict__ bits1,
                                                uint64_t* __restrict__ bits2) {
    int n = blockIdx.y;
    if (blockIdx.x >= 25) {              // halo zeroing: 452 cells/image
        int t = (blockIdx.x - 25) * 256 + threadIdx.x;
        if (t < 2 * PW + 2 * Hh) {
            int cell;
            if      (t < PW)          cell = t;                          // top row
            else if (t < 2 * PW)      cell = 113 * PW + (t - PW);        // bottom row
            else if (t < 2 * PW + Hh) cell = (t - 2 * PW + 1) * PW;      // left col
            else                      cell = (t - 2 * PW - Hh + 1) * PW + 113; // right col
            size_t bi = (size_t)n * PHW + cell;
            bits1[bi] = 0; bits2[bi] = 0;
        }
        return;
    }
    int p = blockIdx.x * 256 + threadIdx.x;
    if (p >= NPAIR) return;
    int h = p / WROW, w0 = (p - h * WROW) * 2;
    int hw = h * Ww + w0;
    const float* xp = x + (size_t)n * Cc * HWp + hw;
    size_t bi = (size_t)n * PHW + (h + 1) * PW + (w0 + 1);

    f32x2 cur[16], nxt[16];
    #pragma unroll
    for (int j = 0; j < 16; ++j) cur[j] = *(const f32x2*)(xp + (size_t)j * HWp);

    uint64_t ma = 0, mb = 0;
    #pragma unroll 1
    for (int cc = 0; cc < Cc - 16; cc += 16) {
        #pragma unroll
        for (int j = 0; j < 16; ++j)
            nxt[j] = *(const f32x2*)(xp + (size_t)(cc + 16 + j) * HWp);
        MEMFENCE();
        #pragma unroll
        for (int j = 0; j < 16; ++j) {
            float bb = b11[cc + j];
            if (cur[j].x + bb < 0.f) ma |= (1ull << (cc + j));
            if (cur[j].y + bb < 0.f) mb |= (1ull << (cc + j));
        }
        MEMFENCE();
        #pragma unroll
        for (int j = 0; j < 16; ++j) cur[j] = nxt[j];
    }
    #pragma unroll
    for (int j = 0; j < 16; ++j) {        // tail batch (cc = 48)
        float bb = b11[48 + j];
        if (cur[j].x + bb < 0.f) ma |= (1ull << (48 + j));
        if (cur[j].y + bb < 0.f) mb |= (1ull << (48 + j));
    }
    bits1[bi] = ma; bits1[bi + 1] = mb;
}

// conv1 on a pixel-pair: 12-word bits window shared by both pixels; residual x
// prefetched 8-channels-ahead in f32x2; epilogue -> out1 (f16x2) + bits2 pair.
template <typename OutT>
__global__ __launch_bounds__(256, 4) void conv1_ep(
        const float* __restrict__ x, const uint64_t* __restrict__ bits1,
        const uint64_t* __restrict__ wb, const float* __restrict__ asc,
        const int* __restrict__ cint,
        const float* __restrict__ b12, const float* __restrict__ a1,
        const float* __restrict__ b13, const float* __restrict__ b21,
        OutT* __restrict__ out1, uint64_t* __restrict__ bits2) {
    __shared__ int lci[Cc * 10];               // [o][t9], stride 10 (bank-safe)
    for (int i = threadIdx.x; i < Cc * 10; i += 256) lci[i] = cint[i];
    __syncthreads();

    int p = blockIdx.x * 256 + threadIdx.x;
    if (p >= NPAIR) return;
    int n = blockIdx.y;
    int h = p / WROW, w0 = (p - h * WROW) * 2;
    int hw = h * Ww + w0;
    int rowp = (h == 0) ? 0 : (h == Hh - 1) ? 6 : 3;
    int t9a = rowp + ((w0 == 0) ? 0 : 1);
    int t9b = rowp + ((w0 + 1 == Ww - 1) ? 2 : 1);

    const uint64_t* bp = bits1 + (size_t)n * PHW + (h + 1) * PW + (w0 + 1);
    uint64_t q0[4], q1[4], q2[4];
    #pragma unroll
    for (int c = 0; c < 4; ++c) {
        q0[c] = bp[-PW - 1 + c]; q1[c] = bp[-1 + c]; q2[c] = bp[PW - 1 + c];
    }

    const float* xp = x + (size_t)n * Cc * HWp + hw;
    OutT* op = out1 + (size_t)n * Cc * HWp + hw;
    uint64_t m2a = 0, m2b = 0;

    f32x2 cur[8], nxt[8];
    #pragma unroll
    for (int j = 0; j < 8; ++j) cur[j] = *(const f32x2*)(xp + (size_t)j * HWp);

    #pragma unroll 1
    for (int oc = 0; oc <= Cc - 8; oc += 8) {
        if (oc < Cc - 8) {
            #pragma unroll
            for (int j = 0; j < 8; ++j)
                nxt[j] = *(const f32x2*)(xp + (size_t)(oc + 8 + j) * HWp);
        }
        MEMFENCE();
        #pragma unroll
        for (int j = 0; j < 8; ++j) {
            int o = oc + j;
            const uint64_t* wo = wb + o * 9;   // wave-uniform -> s_load
            uint64_t t0 = wo[0], t1 = wo[1], t2 = wo[2], t3 = wo[3], t4 = wo[4],
                     t5 = wo[5], t6 = wo[6], t7 = wo[7], t8 = wo[8];
            int sa = (int)__popcll(q0[0] ^ t0) + (int)__popcll(q0[1] ^ t1) + (int)__popcll(q0[2] ^ t2)
                   + (int)__popcll(q1[0] ^ t3) + (int)__popcll(q1[1] ^ t4) + (int)__popcll(q1[2] ^ t5)
                   + (int)__popcll(q2[0] ^ t6) + (int)__popcll(q2[1] ^ t7) + (int)__popcll(q2[2] ^ t8);
            int sb = (int)__popcll(q0[1] ^ t0) + (int)__popcll(q0[2] ^ t1) + (int)__popcll(q0[3] ^ t2)
                   + (int)__popcll(q1[1] ^ t3) + (int)__popcll(q1[2] ^ t4) + (int)__popcll(q1[3] ^ t5)
                   + (int)__popcll(q2[1] ^ t6) + (int)__popcll(q2[2] ^ t7) + (int)__popcll(q2[3] ^ t8);
            int ca = lci[o * 10 + t9a];
            int cb = lci[o * 10 + t9b];
            float sc = asc[o], B2 = b12[o], A = a1[o], B3 = b13[o], B1 = b21[o];
            float va = fmaf(sc, (float)(ca - 2 * sa), cur[j].x);
            float vb = fmaf(sc, (float)(cb - 2 * sb), cur[j].y);
            va += B2; va = va >= 0.f ? va : A * va; va += B3;
            vb += B2; vb = vb >= 0.f ? vb : A * vb; vb += B3;
            if constexpr (sizeof(OutT) == 2) {
                f16x2 hv; hv.x = (_Float16)va; hv.y = (_Float16)vb;
                *(f16x2*)(op + (size_t)o * HWp) = hv;
            } else {
                f32x2 fv; fv.x = va; fv.y = vb;
                *(f32x2*)(op + (size_t)o * HWp) = fv;
            }
            if (va + B1 < 0.f) m2a |= (1ull << o);
            if (vb + B1 < 0.f) m2b |= (1ull << o);
        }
        MEMFENCE();
        #pragma unroll
        for (int j = 0; j < 8; ++j) cur[j] = nxt[j];
    }
    size_t b2 = (size_t)n * PHW + (h + 1) * PW + (w0 + 1);
    bits2[b2] = m2a; bits2[b2 + 1] = m2b;
}

// conv2: residual kept as raw f16x2 in the prefetch buffer (converted in the
// compute phase); final out stored nontemporal (no reuse).
template <typename InT>
__global__ __launch_bounds__(256, 4) void conv2_ep(
        const uint64_t* __restrict__ bits2, const InT* __restrict__ out1,
        const uint64_t* __restrict__ wb, const float* __restrict__ asc,
        const int* __restrict__ cint,
        const float* __restrict__ b22, const float* __restrict__ a2,
        const float* __restrict__ b23, float* __restrict__ out) {
    __shared__ int lci[Cc * 10];
    for (int i = threadIdx.x; i < Cc * 10; i += 256) lci[i] = cint[i];
    __syncthreads();

    int p = blockIdx.x * 256 + threadIdx.x;
    if (p >= NPAIR) return;
    int n = blockIdx.y;
    int h = p / WROW, w0 = (p - h * WROW) * 2;
    int hw = h * Ww + w0;
    int rowp = (h == 0) ? 0 : (h == Hh - 1) ? 6 : 3;
    int t9a = rowp + ((w0 == 0) ? 0 : 1);
    int t9b = rowp + ((w0 + 1 == Ww - 1) ? 2 : 1);

    const uint64_t* bp = bits2 + (size_t)n * PHW + (h + 1) * PW + (w0 + 1);
    uint64_t q0[4], q1[4], q2[4];
    #pragma unroll
    for (int c = 0; c < 4; ++c) {
        q0[c] = bp[-PW - 1 + c]; q1[c] = bp[-1 + c]; q2[c] = bp[PW - 1 + c];
    }

    const InT* ip = out1 + (size_t)n * Cc * HWp + hw;
    float* op = out + (size_t)n * Cc * HWp + hw;

    f16x2 curh[8], nxth[8];
    f32x2 curf[8], nxtf[8];
    if constexpr (sizeof(InT) == 2) {
        #pragma unroll
        for (int j = 0; j < 8; ++j) curh[j] = *(const f16x2*)(ip + (size_t)j * HWp);
    } else {
        #pragma unroll
        for (int j = 0; j < 8; ++j) curf[j] = *(const f32x2*)(ip + (size_t)j * HWp);
    }

    #pragma unroll 1
    for (int oc = 0; oc <= Cc - 8; oc += 8) {
        if (oc < Cc - 8) {
            if constexpr (sizeof(InT) == 2) {
                #pragma unroll
                for (int j = 0; j < 8; ++j)
                    nxth[j] = *(const f16x2*)(ip + (size_t)(oc + 8 + j) * HWp);
            } else {
                #pragma unroll
                for (int j = 0; j < 8; ++j)
                    nxtf[j] = *(const f32x2*)(ip + (size_t)(oc + 8 + j) * HWp);
            }
        }
        MEMFENCE();
        #pragma unroll
        for (int j = 0; j < 8; ++j) {
            int o = oc + j;
            const uint64_t* wo = wb + o * 9;
            uint64_t t0 = wo[0], t1 = wo[1], t2 = wo[2], t3 = wo[3], t4 = wo[4],
                     t5 = wo[5], t6 = wo[6], t7 = wo[7], t8 = wo[8];
            int sa = (int)__popcll(q0[0] ^ t0) + (int)__popcll(q0[1] ^ t1) + (int)__popcll(q0[2] ^ t2)
                   + (int)__popcll(q1[0] ^ t3) + (int)__popcll(q1[1] ^ t4) + (int)__popcll(q1[2] ^ t5)
                   + (int)__popcll(q2[0] ^ t6) + (int)__popcll(q2[1] ^ t7) + (int)__popcll(q2[2] ^ t8);
            int sb = (int)__popcll(q0[1] ^ t0) + (int)__popcll(q0[2] ^ t1) + (int)__popcll(q0[3] ^ t2)
                   + (int)__popcll(q1[1] ^ t3) + (int)__popcll(q1[2] ^ t4) + (int)__popcll(q1[3] ^ t5)
                   + (int)__popcll(q2[1] ^ t6) + (int)__popcll(q2[2] ^ t7) + (int)__popcll(q2[3] ^ t8);
            int ca = lci[o * 10 + t9a];
            int cb = lci[o * 10 + t9b];
            float ra, rb;
            if constexpr (sizeof(InT) == 2) { ra = (float)curh[j].x; rb = (float)curh[j].y; }
            else                            { ra = curf[j].x;        rb = curf[j].y; }
            float sc = asc[o], B2 = b22[o], A = a2[o], B3 = b23[o];
            float va = fmaf(sc, (float)(ca - 2 * sa), ra);
            float vb = fmaf(sc, (float)(cb - 2 * sb), rb);
            va += B2; va = va >= 0.f ? va : A * va; va += B3;
            vb += B2; vb = vb >= 0.f ? vb : A * vb; vb += B3;
            f32x2 fv; fv.x = va; fv.y = vb;
            __builtin_nontemporal_store(fv, (f32x2*)(op + (size_t)o * HWp));
        }
        MEMFENCE();
        if constexpr (sizeof(InT) == 2) {
            #pragma unroll
            for (int j = 0; j < 8; ++j) curh[j] = nxth[j];
        } else {
            #pragma unroll
            for (int j = 0; j < 8; ++j) curf[j] = nxtf[j];
        }
    }
}

extern "C" void kernel_launch(void* const* d_in, const int* in_sizes, int n_in,
                              void* d_out, int out_size, void* d_ws, size_t ws_size,
                              hipStream_t stream) {
    const float* x    = (const float*)d_in[0];
    const float* w3   = (const float*)d_in[1];
    const float* wpw  = (const float*)d_in[2];
    const float* b11  = (const float*)d_in[3];
    const float* b12  = (const float*)d_in[4];
    const float* b13  = (const float*)d_in[5];
    const float* b21  = (const float*)d_in[6];
    const float* b22  = (const float*)d_in[7];
    const float* b23  = (const float*)d_in[8];
    const float* a1   = (const float*)d_in[9];
    const float* a2   = (const float*)d_in[10];

    char* ws = (char*)d_ws;
    uint64_t* wb1   = (uint64_t*)(ws + WB1_OFF);
    uint64_t* wb2   = (uint64_t*)(ws + WB2_OFF);
    float*    asc1  = (float*)(ws + ASC1_OFF);
    float*    asc2  = (float*)(ws + ASC2_OFF);
    int*      ci1   = (int*)(ws + CI1_OFF);
    int*      ci2   = (int*)(ws + CI2_OFF);
    uint64_t* bits1 = (uint64_t*)(ws + BITS1_OFF);
    uint64_t* bits2 = (uint64_t*)(ws + BITS2_OFF);
    float*    out   = (float*)d_out;

    dim3 pgrid(27, Bn);                  // 25 pair-blocks + 2 halo-zero blocks
    dim3 cgrid((NPAIR + 255) / 256, Bn); // 25 x 32

    prep_weights<<<128, 64, 0, stream>>>(w3, wpw, wb1, wb2, asc1, asc2, ci1, ci2);
    pack1<<<pgrid, 256, 0, stream>>>(x, b11, bits1, bits2);

    if (ws_size >= WS_NEED) {
        __half* out1h = (__half*)(ws + OUT1H_OFF);
        conv1_ep<__half><<<cgrid, 256, 0, stream>>>(x, bits1, wb1, asc1, ci1,
                                                    b12, a1, b13, b21, out1h, bits2);
        conv2_ep<__half><<<cgrid, 256, 0, stream>>>(bits2, out1h, wb2, asc2, ci2,
                                                    b22, a2, b23, out);
    } else {
        conv1_ep<float><<<cgrid, 256, 0, stream>>>(x, bits1, wb1, asc1, ci1,
                                                   b12, a1, b13, b21, out, bits2);
        conv2_ep<float><<<cgrid, 256, 0, stream>>>(bits2, out, wb2, asc2, ci2,
                                                   b22, a2, b23, out);
    }
}

// Round 4
// 272.245 us; speedup vs baseline: 1.1486x; 1.0823x over previous
//
#include <hip/hip_runtime.h>
#include <hip/hip_fp16.h>
#include <stdint.h>

#define Bn 32
#define Cc 64
#define Hh 112
#define Ww 112
#define HWp (Hh*Ww)            // 12544
#define NPIX (Bn*HWp)          // 401408
#define PW 114                 // padded width
#define PHW (PW*PW)            // 12996 padded cells per image
#define NPAIR (HWp/2)          // 6272 pixel-pairs per image
#define WROW (Ww/2)            // 56 pairs per row
#define ALPHA 0.25f
#define CSP 4                  // channel-split blocks per conv
#define CPB (Cc/CSP)           // 16 channels per conv block

typedef float    f32x2 __attribute__((ext_vector_type(2)));
typedef _Float16 f16x2 __attribute__((ext_vector_type(2)));

// workspace layout (bytes)
#define WB1_OFF   0                      // uint64[64*9]
#define WB2_OFF   4608
#define ASC1_OFF  9216                   // float[64]  (= ALPHA * mean|w|)
#define ASC2_OFF  9472
#define CI1_OFF   9728                   // int[64*10] (padded stride 10)
#define CI2_OFF   12288                  // int[64*10]
#define BITS1_OFF 16384                  // uint64[Bn*PHW] (padded, halo=0)
#define BITS2_OFF (16384 + 3326976)
#define OUT1H_OFF (16384 + 2*3326976)    // __half[NPIX*Cc] (fp16 path)
#define WS_NEED   (OUT1H_OFF + (size_t)NPIX*Cc*2)

// Compiler memory barrier: loads issued before it cannot sink past it,
// so a preload batch is guaranteed in flight under the following compute.
#define MEMFENCE() asm volatile("" ::: "memory")

// 128 blocks x 64 lanes; block b<64 -> conv1 tables (o=b), else conv2.
__global__ __launch_bounds__(64) void prep_weights(
        const float* __restrict__ w3, const float* __restrict__ wpw,
        uint64_t* __restrict__ wb1, uint64_t* __restrict__ wb2,
        float* __restrict__ asc1, float* __restrict__ asc2,
        int* __restrict__ ci1, int* __restrict__ ci2) {
    int b = blockIdx.x;
    int lane = threadIdx.x;
    const float* w  = (b < 64) ? w3   : wpw;
    uint64_t* wbits = (b < 64) ? wb1  : wb2;
    float*    ascp  = (b < 64) ? asc1 : asc2;
    int*      cip   = (b < 64) ? ci1  : ci2;
    int o = b & 63;
    const float* wp = w + ((size_t)o * Cc + lane) * 9;
    float v[9]; float asum = 0.f;
    #pragma unroll
    for (int t = 0; t < 9; ++t) { v[t] = wp[t]; asum += fabsf(v[t]); }
    uint64_t bal[9];
    #pragma unroll
    for (int t = 0; t < 9; ++t) bal[t] = __ballot(v[t] < 0.f);
    if (lane < 9) {
        wbits[o * 9 + lane] = bal[lane];
        int ty = lane, tr = ty / 3, tc = ty % 3;
        int sum = 0;
        #pragma unroll
        for (int t = 0; t < 9; ++t) {
            int r = t / 3, c = t % 3;
            bool inv = (tr == 0 && r == 0) || (tr == 2 && r == 2) ||
                       (tc == 0 && c == 0) || (tc == 2 && c == 2);
            if (inv) sum += 64 - 2 * (int)__popcll(bal[t]);
        }
        cip[o * 10 + ty] = 576 - sum;       // padded stride 10
    }
    #pragma unroll
    for (int off = 32; off > 0; off >>= 1) asum += __shfl_down(asum, off, 64);
    if (lane == 0) ascp[o] = ALPHA * asum * (1.f / 576.f);
}

// One thread per interior pixel-PAIR; z-split: each z handles 32 channels and
// writes its u32 half of the bits1 cell. Halo zeroed by z==0 blocks 25,26.
__global__ __launch_bounds__(256, 4) void pack1(const float* __restrict__ x,
                                                const float* __restrict__ b11,
                                                uint64_t* __restrict__ bits1,
                                                uint64_t* __restrict__ bits2) {
    int n = blockIdx.y;
    int z = blockIdx.z;
    if (blockIdx.x >= 25) {              // halo zeroing: 452 cells/image
        if (z) return;
        int t = (blockIdx.x - 25) * 256 + threadIdx.x;
        if (t < 2 * PW + 2 * Hh) {
            int cell;
            if      (t < PW)          cell = t;                          // top row
            else if (t < 2 * PW)      cell = 113 * PW + (t - PW);        // bottom row
            else if (t < 2 * PW + Hh) cell = (t - 2 * PW + 1) * PW;      // left col
            else                      cell = (t - 2 * PW - Hh + 1) * PW + 113; // right col
            size_t bi = (size_t)n * PHW + cell;
            bits1[bi] = 0; bits2[bi] = 0;
        }
        return;
    }
    int p = blockIdx.x * 256 + threadIdx.x;
    if (p >= NPAIR) return;
    int h = p / WROW, w0 = (p - h * WROW) * 2;
    int hw = h * Ww + w0;
    int cb = z * 32;
    const float* xp = x + ((size_t)n * Cc + cb) * HWp + hw;
    size_t bi = (size_t)n * PHW + (h + 1) * PW + (w0 + 1);

    f32x2 v[32];
    #pragma unroll
    for (int j = 0; j < 32; ++j) v[j] = *(const f32x2*)(xp + (size_t)j * HWp);
    MEMFENCE();

    uint32_t ma = 0, mb = 0;
    #pragma unroll
    for (int j = 0; j < 32; ++j) {
        float bb = b11[cb + j];
        if (v[j].x + bb < 0.f) ma |= (1u << j);
        if (v[j].y + bb < 0.f) mb |= (1u << j);
    }
    uint32_t* wp1 = (uint32_t*)(bits1 + bi);
    wp1[z]     = ma;        // cell a, channels [32z, 32z+32)
    wp1[2 + z] = mb;        // cell a+1 (next u64 = +8 B = +2 u32)
}

// conv1 on a pixel-pair, channels [16z, 16z+16): 12-word bits window shared by
// both pixels; 16 residual f32x2 preloaded behind one fence; epilogue ->
// out1 (f16x2) + u16 slice of the bits2 cells.
template <typename OutT>
__global__ __launch_bounds__(256, 4) void conv1_ep(
        const float* __restrict__ x, const uint64_t* __restrict__ bits1,
        const uint64_t* __restrict__ wb, const float* __restrict__ asc,
        const int* __restrict__ cint,
        const float* __restrict__ b12, const float* __restrict__ a1,
        const float* __restrict__ b13, const float* __restrict__ b21,
        OutT* __restrict__ out1, uint64_t* __restrict__ bits2) {
    __shared__ int lci[CPB * 10];              // this block's channels, stride 10
    int zb = blockIdx.z;
    int ob = zb * CPB;
    for (int i = threadIdx.x; i < CPB * 10; i += 256) lci[i] = cint[ob * 10 + i];
    __syncthreads();

    int p = blockIdx.x * 256 + threadIdx.x;
    if (p >= NPAIR) return;
    int n = blockIdx.y;
    int h = p / WROW, w0 = (p - h * WROW) * 2;
    int hw = h * Ww + w0;
    int rowp = (h == 0) ? 0 : (h == Hh - 1) ? 6 : 3;
    int t9a = rowp + ((w0 == 0) ? 0 : 1);
    int t9b = rowp + ((w0 + 1 == Ww - 1) ? 2 : 1);

    const uint64_t* bp = bits1 + (size_t)n * PHW + (h + 1) * PW + (w0 + 1);
    uint64_t q0[4], q1[4], q2[4];
    #pragma unroll
    for (int c = 0; c < 4; ++c) {
        q0[c] = bp[-PW - 1 + c]; q1[c] = bp[-1 + c]; q2[c] = bp[PW - 1 + c];
    }

    const float* xp = x + ((size_t)n * Cc + ob) * HWp + hw;
    OutT* op = out1 + ((size_t)n * Cc + ob) * HWp + hw;

    f32x2 cur[CPB];
    #pragma unroll
    for (int j = 0; j < CPB; ++j) cur[j] = *(const f32x2*)(xp + (size_t)j * HWp);
    MEMFENCE();

    uint32_t m2a = 0, m2b = 0;
    #pragma unroll
    for (int j = 0; j < CPB; ++j) {
        int o = ob + j;
        const uint64_t* wo = wb + o * 9;       // wave-uniform -> s_load
        uint64_t t0 = wo[0], t1 = wo[1], t2 = wo[2], t3 = wo[3], t4 = wo[4],
                 t5 = wo[5], t6 = wo[6], t7 = wo[7], t8 = wo[8];
        int sa = (int)__popcll(q0[0] ^ t0) + (int)__popcll(q0[1] ^ t1) + (int)__popcll(q0[2] ^ t2)
               + (int)__popcll(q1[0] ^ t3) + (int)__popcll(q1[1] ^ t4) + (int)__popcll(q1[2] ^ t5)
               + (int)__popcll(q2[0] ^ t6) + (int)__popcll(q2[1] ^ t7) + (int)__popcll(q2[2] ^ t8);
        int sb = (int)__popcll(q0[1] ^ t0) + (int)__popcll(q0[2] ^ t1) + (int)__popcll(q0[3] ^ t2)
               + (int)__popcll(q1[1] ^ t3) + (int)__popcll(q1[2] ^ t4) + (int)__popcll(q1[3] ^ t5)
               + (int)__popcll(q2[1] ^ t6) + (int)__popcll(q2[2] ^ t7) + (int)__popcll(q2[3] ^ t8);
        int ca = lci[j * 10 + t9a];
        int cb = lci[j * 10 + t9b];
        float sc = asc[o], B2 = b12[o], Am1 = a1[o] - 1.0f, B3 = b13[o], B1 = b21[o];
        float va = fmaf(sc, (float)(ca - 2 * sa), cur[j].x);
        float vb = fmaf(sc, (float)(cb - 2 * sb), cur[j].y);
        va += B2; va = fmaf(fminf(va, 0.f), Am1, va); va += B3;
        vb += B2; vb = fmaf(fminf(vb, 0.f), Am1, vb); vb += B3;
        if constexpr (sizeof(OutT) == 2) {
            f16x2 hv; hv.x = (_Float16)va; hv.y = (_Float16)vb;
            *(f16x2*)(op + (size_t)j * HWp) = hv;
        } else {
            f32x2 fv; fv.x = va; fv.y = vb;
            *(f32x2*)(op + (size_t)j * HWp) = fv;
        }
        if (va + B1 < 0.f) m2a |= (1u << j);
        if (vb + B1 < 0.f) m2b |= (1u << j);
    }
    uint16_t* b2p = (uint16_t*)(bits2 + (size_t)n * PHW + (h + 1) * PW + (w0 + 1));
    b2p[zb]     = (uint16_t)m2a;   // cell a, channels [16z, 16z+16)
    b2p[4 + zb] = (uint16_t)m2b;   // cell a+1 (+8 B = +4 u16)
}

// conv2: same structure; residual from out1 (f16x2), final out f32x2 nontemporal.
template <typename InT>
__global__ __launch_bounds__(256, 4) void conv2_ep(
        const uint64_t* __restrict__ bits2, const InT* __restrict__ out1,
        const uint64_t* __restrict__ wb, const float* __restrict__ asc,
        const int* __restrict__ cint,
        const float* __restrict__ b22, const float* __restrict__ a2,
        const float* __restrict__ b23, float* __restrict__ out) {
    __shared__ int lci[CPB * 10];
    int zb = blockIdx.z;
    int ob = zb * CPB;
    for (int i = threadIdx.x; i < CPB * 10; i += 256) lci[i] = cint[ob * 10 + i];
    __syncthreads();

    int p = blockIdx.x * 256 + threadIdx.x;
    if (p >= NPAIR) return;
    int n = blockIdx.y;
    int h = p / WROW, w0 = (p - h * WROW) * 2;
    int hw = h * Ww + w0;
    int rowp = (h == 0) ? 0 : (h == Hh - 1) ? 6 : 3;
    int t9a = rowp + ((w0 == 0) ? 0 : 1);
    int t9b = rowp + ((w0 + 1 == Ww - 1) ? 2 : 1);

    const uint64_t* bp = bits2 + (size_t)n * PHW + (h + 1) * PW + (w0 + 1);
    uint64_t q0[4], q1[4], q2[4];
    #pragma unroll
    for (int c = 0; c < 4; ++c) {
        q0[c] = bp[-PW - 1 + c]; q1[c] = bp[-1 + c]; q2[c] = bp[PW - 1 + c];
    }

    const InT* ip = out1 + ((size_t)n * Cc + ob) * HWp + hw;
    float* op = out + ((size_t)n * Cc + ob) * HWp + hw;

    f16x2 curh[CPB];
    f32x2 curf[CPB];
    if constexpr (sizeof(InT) == 2) {
        #pragma unroll
        for (int j = 0; j < CPB; ++j) curh[j] = *(const f16x2*)(ip + (size_t)j * HWp);
    } else {
        #pragma unroll
        for (int j = 0; j < CPB; ++j) curf[j] = *(const f32x2*)(ip + (size_t)j * HWp);
    }
    MEMFENCE();

    #pragma unroll
    for (int j = 0; j < CPB; ++j) {
        int o = ob + j;
        const uint64_t* wo = wb + o * 9;
        uint64_t t0 = wo[0], t1 = wo[1], t2 = wo[2], t3 = wo[3], t4 = wo[4],
                 t5 = wo[5], t6 = wo[6], t7 = wo[7], t8 = wo[8];
        int sa = (int)__popcll(q0[0] ^ t0) + (int)__popcll(q0[1] ^ t1) + (int)__popcll(q0[2] ^ t2)
               + (int)__popcll(q1[0] ^ t3) + (int)__popcll(q1[1] ^ t4) + (int)__popcll(q1[2] ^ t5)
               + (int)__popcll(q2[0] ^ t6) + (int)__popcll(q2[1] ^ t7) + (int)__popcll(q2[2] ^ t8);
        int sb = (int)__popcll(q0[1] ^ t0) + (int)__popcll(q0[2] ^ t1) + (int)__popcll(q0[3] ^ t2)
               + (int)__popcll(q1[1] ^ t3) + (int)__popcll(q1[2] ^ t4) + (int)__popcll(q1[3] ^ t5)
               + (int)__popcll(q2[1] ^ t6) + (int)__popcll(q2[2] ^ t7) + (int)__popcll(q2[3] ^ t8);
        int ca = lci[j * 10 + t9a];
        int cb = lci[j * 10 + t9b];
        float ra, rb;
        if constexpr (sizeof(InT) == 2) { ra = (float)curh[j].x; rb = (float)curh[j].y; }
        else                            { ra = curf[j].x;        rb = curf[j].y; }
        float sc = asc[o], B2 = b22[o], Am1 = a2[o] - 1.0f, B3 = b23[o];
        float va = fmaf(sc, (float)(ca - 2 * sa), ra);
        float vb = fmaf(sc, (float)(cb - 2 * sb), rb);
        va += B2; va = fmaf(fminf(va, 0.f), Am1, va); va += B3;
        vb += B2; vb = fmaf(fminf(vb, 0.f), Am1, vb); vb += B3;
        f32x2 fv; fv.x = va; fv.y = vb;
        __builtin_nontemporal_store(fv, (f32x2*)(op + (size_t)j * HWp));
    }
}

extern "C" void kernel_launch(void* const* d_in, const int* in_sizes, int n_in,
                              void* d_out, int out_size, void* d_ws, size_t ws_size,
                              hipStream_t stream) {
    const float* x    = (const float*)d_in[0];
    const float* w3   = (const float*)d_in[1];
    const float* wpw  = (const float*)d_in[2];
    const float* b11  = (const float*)d_in[3];
    const float* b12  = (const float*)d_in[4];
    const float* b13  = (const float*)d_in[5];
    const float* b21  = (const float*)d_in[6];
    const float* b22  = (const float*)d_in[7];
    const float* b23  = (const float*)d_in[8];
    const float* a1   = (const float*)d_in[9];
    const float* a2   = (const float*)d_in[10];

    char* ws = (char*)d_ws;
    uint64_t* wb1   = (uint64_t*)(ws + WB1_OFF);
    uint64_t* wb2   = (uint64_t*)(ws + WB2_OFF);
    float*    asc1  = (float*)(ws + ASC1_OFF);
    float*    asc2  = (float*)(ws + ASC2_OFF);
    int*      ci1   = (int*)(ws + CI1_OFF);
    int*      ci2   = (int*)(ws + CI2_OFF);
    uint64_t* bits1 = (uint64_t*)(ws + BITS1_OFF);
    uint64_t* bits2 = (uint64_t*)(ws + BITS2_OFF);
    float*    out   = (float*)d_out;

    dim3 pgrid(27, Bn, 2);               // 25 pair-blocks + 2 halo blocks; 2 ch-slices
    dim3 cgrid((NPAIR + 255) / 256, Bn, CSP);  // 25 x 32 x 4 = 3200 blocks

    prep_weights<<<128, 64, 0, stream>>>(w3, wpw, wb1, wb2, asc1, asc2, ci1, ci2);
    pack1<<<pgrid, 256, 0, stream>>>(x, b11, bits1, bits2);

    if (ws_size >= WS_NEED) {
        __half* out1h = (__half*)(ws + OUT1H_OFF);
        conv1_ep<__half><<<cgrid, 256, 0, stream>>>(x, bits1, wb1, asc1, ci1,
                                                    b12, a1, b13, b21, out1h, bits2);
        conv2_ep<__half><<<cgrid, 256, 0, stream>>>(bits2, out1h, wb2, asc2, ci2,
                                                    b22, a2, b23, out);
    } else {
        conv1_ep<float><<<cgrid, 256, 0, stream>>>(x, bits1, wb1, asc1, ci1,
                                                   b12, a1, b13, b21, out, bits2);
        conv2_ep<float><<<cgrid, 256, 0, stream>>>(bits2, out, wb2, asc2, ci2,
                                                   b22, a2, b23, out);
    }
}

// Round 5
// 271.643 us; speedup vs baseline: 1.1512x; 1.0022x over previous
//
#include <hip/hip_runtime.h>
#include <hip/hip_fp16.h>
#include <stdint.h>

#define Bn 32
#define Cc 64
#define Hh 112
#define Ww 112
#define HWp (Hh*Ww)            // 12544
#define NPIX (Bn*HWp)          // 401408
#define PW 114                 // padded width
#define PHW (PW*PW)            // 12996 padded cells per image
#define NQUAD (HWp/4)          // 3136 pixel-quads per image
#define QROW (Ww/4)            // 28 quads per row
#define ALPHA 0.25f
#define CSPC 8                 // conv channel-split blocks
#define CPB (Cc/CSPC)          // 8 channels per conv block
#define PSP 4                  // pack1 channel-split blocks (16 ch each)

typedef float    f32x2 __attribute__((ext_vector_type(2)));
typedef float    f32x4 __attribute__((ext_vector_type(4)));
typedef _Float16 f16x2 __attribute__((ext_vector_type(2)));
typedef _Float16 f16x4 __attribute__((ext_vector_type(4)));

// workspace layout (bytes)
#define WB1_OFF   0                      // uint64[64*9]
#define WB2_OFF   4608
#define ASC1_OFF  9216                   // float[64]  (= ALPHA * mean|w|)
#define ASC2_OFF  9472
#define CI1_OFF   9728                   // int[64*10] (padded stride 10)
#define CI2_OFF   12288                  // int[64*10]
#define BITS1_OFF 16384                  // uint64[Bn*PHW] (padded, halo=0)
#define BITS2_OFF (16384 + 3326976)
#define OUT1H_OFF (16384 + 2*3326976)    // __half[NPIX*Cc] (fp16 path)
#define WS_NEED   (OUT1H_OFF + (size_t)NPIX*Cc*2)

// Compiler memory barrier: loads issued before it cannot sink past it,
// so a preload batch is guaranteed in flight under the following compute.
#define MEMFENCE() asm volatile("" ::: "memory")

// 128 blocks x 64 lanes; block b<64 -> conv1 tables (o=b), else conv2.
__global__ __launch_bounds__(64) void prep_weights(
        const float* __restrict__ w3, const float* __restrict__ wpw,
        uint64_t* __restrict__ wb1, uint64_t* __restrict__ wb2,
        float* __restrict__ asc1, float* __restrict__ asc2,
        int* __restrict__ ci1, int* __restrict__ ci2) {
    int b = blockIdx.x;
    int lane = threadIdx.x;
    const float* w  = (b < 64) ? w3   : wpw;
    uint64_t* wbits = (b < 64) ? wb1  : wb2;
    float*    ascp  = (b < 64) ? asc1 : asc2;
    int*      cip   = (b < 64) ? ci1  : ci2;
    int o = b & 63;
    const float* wp = w + ((size_t)o * Cc + lane) * 9;
    float v[9]; float asum = 0.f;
    #pragma unroll
    for (int t = 0; t < 9; ++t) { v[t] = wp[t]; asum += fabsf(v[t]); }
    uint64_t bal[9];
    #pragma unroll
    for (int t = 0; t < 9; ++t) bal[t] = __ballot(v[t] < 0.f);
    if (lane < 9) {
        wbits[o * 9 + lane] = bal[lane];
        int ty = lane, tr = ty / 3, tc = ty % 3;
        int sum = 0;
        #pragma unroll
        for (int t = 0; t < 9; ++t) {
            int r = t / 3, c = t % 3;
            bool inv = (tr == 0 && r == 0) || (tr == 2 && r == 2) ||
                       (tc == 0 && c == 0) || (tc == 2 && c == 2);
            if (inv) sum += 64 - 2 * (int)__popcll(bal[t]);
        }
        cip[o * 10 + ty] = 576 - sum;       // padded stride 10
    }
    #pragma unroll
    for (int off = 32; off > 0; off >>= 1) asum += __shfl_down(asum, off, 64);
    if (lane == 0) ascp[o] = ALPHA * asum * (1.f / 576.f);
}

// One thread per interior pixel-QUAD; z in [0,4): 16 channels each, writes the
// u16 slice of each of its 4 bits1 cells. Halo zeroed by z==0 blocks 13,14.
__global__ __launch_bounds__(256, 4) void pack1(const float* __restrict__ x,
                                                const float* __restrict__ b11,
                                                uint64_t* __restrict__ bits1,
                                                uint64_t* __restrict__ bits2) {
    int n = blockIdx.y;
    int z = blockIdx.z;
    if (blockIdx.x >= 13) {              // halo zeroing: 452 cells/image
        if (z) return;
        int t = (blockIdx.x - 13) * 256 + threadIdx.x;
        if (t < 2 * PW + 2 * Hh) {
            int cell;
            if      (t < PW)          cell = t;                          // top row
            else if (t < 2 * PW)      cell = 113 * PW + (t - PW);        // bottom row
            else if (t < 2 * PW + Hh) cell = (t - 2 * PW + 1) * PW;      // left col
            else                      cell = (t - 2 * PW - Hh + 1) * PW + 113; // right col
            size_t bi = (size_t)n * PHW + cell;
            bits1[bi] = 0; bits2[bi] = 0;
        }
        return;
    }
    int p = blockIdx.x * 256 + threadIdx.x;
    if (p >= NQUAD) return;
    int h = p / QROW, qx = p - h * QROW;
    int w0 = qx * 4;
    int hw = h * Ww + w0;
    int cb = z * 16;
    const float* xp = x + ((size_t)n * Cc + cb) * HWp + hw;
    size_t bi = (size_t)n * PHW + (h + 1) * PW + (w0 + 1);

    f32x4 v[16];
    #pragma unroll
    for (int j = 0; j < 16; ++j) v[j] = *(const f32x4*)(xp + (size_t)j * HWp);
    MEMFENCE();

    uint32_t ma = 0, mb = 0, mc = 0, md = 0;
    #pragma unroll
    for (int j = 0; j < 16; ++j) {
        float bb = b11[cb + j];
        if (v[j].x + bb < 0.f) ma |= (1u << j);
        if (v[j].y + bb < 0.f) mb |= (1u << j);
        if (v[j].z + bb < 0.f) mc |= (1u << j);
        if (v[j].w + bb < 0.f) md |= (1u << j);
    }
    uint16_t* wp1 = (uint16_t*)(bits1 + bi);   // cell k -> u16 index 4k + z
    wp1[z]      = (uint16_t)ma;
    wp1[4 + z]  = (uint16_t)mb;
    wp1[8 + z]  = (uint16_t)mc;
    wp1[12 + z] = (uint16_t)md;
}

// conv1 on a pixel-quad, channels [8z, 8z+8): 18-word bits window shared by the
// 4 pixels; 8 residual f32x4 preloaded behind one fence; epilogue ->
// out1 (f16x4) + u8 slices of the 4 bits2 cells.
template <typename OutT>
__global__ __launch_bounds__(256, 4) void conv1_ep(
        const float* __restrict__ x, const uint64_t* __restrict__ bits1,
        const uint64_t* __restrict__ wb, const float* __restrict__ asc,
        const int* __restrict__ cint,
        const float* __restrict__ b12, const float* __restrict__ a1,
        const float* __restrict__ b13, const float* __restrict__ b21,
        OutT* __restrict__ out1, uint64_t* __restrict__ bits2) {
    __shared__ int lci[CPB * 10];              // this block's channels, stride 10
    int zb = blockIdx.z;
    int ob = zb * CPB;
    for (int i = threadIdx.x; i < CPB * 10; i += 256) lci[i] = cint[ob * 10 + i];
    __syncthreads();

    int p = blockIdx.x * 256 + threadIdx.x;
    if (p >= NQUAD) return;
    int n = blockIdx.y;
    int h = p / QROW, qx = p - h * QROW;
    int w0 = qx * 4;
    int hw = h * Ww + w0;
    int rowp = (h == 0) ? 0 : (h == Hh - 1) ? 6 : 3;
    int t9a = rowp + ((qx == 0) ? 0 : 1);          // pixel a may touch left edge
    int t9m = rowp + 1;                            // pixels b,c always interior cols
    int t9d = rowp + ((qx == QROW - 1) ? 2 : 1);   // pixel d may touch right edge

    const uint64_t* bp = bits1 + (size_t)n * PHW + (h + 1) * PW + (w0 + 1);
    uint64_t q0[6], q1[6], q2[6];
    #pragma unroll
    for (int c = 0; c < 6; ++c) {
        q0[c] = bp[-PW - 1 + c]; q1[c] = bp[-1 + c]; q2[c] = bp[PW - 1 + c];
    }

    const float* xp = x + ((size_t)n * Cc + ob) * HWp + hw;
    OutT* op = out1 + ((size_t)n * Cc + ob) * HWp + hw;

    f32x4 cur[CPB];
    #pragma unroll
    for (int j = 0; j < CPB; ++j) cur[j] = *(const f32x4*)(xp + (size_t)j * HWp);
    MEMFENCE();

    uint32_t m2a = 0, m2b = 0, m2c = 0, m2d = 0;
    #pragma unroll
    for (int j = 0; j < CPB; ++j) {
        int o = ob + j;
        const uint64_t* wo = wb + o * 9;       // wave-uniform -> s_load
        uint64_t t0 = wo[0], t1 = wo[1], t2 = wo[2], t3 = wo[3], t4 = wo[4],
                 t5 = wo[5], t6 = wo[6], t7 = wo[7], t8 = wo[8];
        int sa = (int)__popcll(q0[0] ^ t0) + (int)__popcll(q0[1] ^ t1) + (int)__popcll(q0[2] ^ t2)
               + (int)__popcll(q1[0] ^ t3) + (int)__popcll(q1[1] ^ t4) + (int)__popcll(q1[2] ^ t5)
               + (int)__popcll(q2[0] ^ t6) + (int)__popcll(q2[1] ^ t7) + (int)__popcll(q2[2] ^ t8);
        int sb = (int)__popcll(q0[1] ^ t0) + (int)__popcll(q0[2] ^ t1) + (int)__popcll(q0[3] ^ t2)
               + (int)__popcll(q1[1] ^ t3) + (int)__popcll(q1[2] ^ t4) + (int)__popcll(q1[3] ^ t5)
               + (int)__popcll(q2[1] ^ t6) + (int)__popcll(q2[2] ^ t7) + (int)__popcll(q2[3] ^ t8);
        int sc_ = (int)__popcll(q0[2] ^ t0) + (int)__popcll(q0[3] ^ t1) + (int)__popcll(q0[4] ^ t2)
               + (int)__popcll(q1[2] ^ t3) + (int)__popcll(q1[3] ^ t4) + (int)__popcll(q1[4] ^ t5)
               + (int)__popcll(q2[2] ^ t6) + (int)__popcll(q2[3] ^ t7) + (int)__popcll(q2[4] ^ t8);
        int sd = (int)__popcll(q0[3] ^ t0) + (int)__popcll(q0[4] ^ t1) + (int)__popcll(q0[5] ^ t2)
               + (int)__popcll(q1[3] ^ t3) + (int)__popcll(q1[4] ^ t4) + (int)__popcll(q1[5] ^ t5)
               + (int)__popcll(q2[3] ^ t6) + (int)__popcll(q2[4] ^ t7) + (int)__popcll(q2[5] ^ t8);
        int ca = lci[j * 10 + t9a];
        int cm = lci[j * 10 + t9m];
        int cd = lci[j * 10 + t9d];
        float scl = asc[o], B2 = b12[o], Am1 = a1[o] - 1.0f, B3 = b13[o], B1 = b21[o];
        float va = fmaf(scl, (float)(ca - 2 * sa), cur[j].x);
        float vb = fmaf(scl, (float)(cm - 2 * sb), cur[j].y);
        float vc = fmaf(scl, (float)(cm - 2 * sc_), cur[j].z);
        float vd = fmaf(scl, (float)(cd - 2 * sd), cur[j].w);
        va += B2; va = fmaf(fminf(va, 0.f), Am1, va); va += B3;
        vb += B2; vb = fmaf(fminf(vb, 0.f), Am1, vb); vb += B3;
        vc += B2; vc = fmaf(fminf(vc, 0.f), Am1, vc); vc += B3;
        vd += B2; vd = fmaf(fminf(vd, 0.f), Am1, vd); vd += B3;
        if constexpr (sizeof(OutT) == 2) {
            f16x4 hv; hv.x = (_Float16)va; hv.y = (_Float16)vb;
            hv.z = (_Float16)vc; hv.w = (_Float16)vd;
            *(f16x4*)(op + (size_t)j * HWp) = hv;
        } else {
            f32x4 fv; fv.x = va; fv.y = vb; fv.z = vc; fv.w = vd;
            *(f32x4*)(op + (size_t)j * HWp) = fv;
        }
        if (va + B1 < 0.f) m2a |= (1u << j);
        if (vb + B1 < 0.f) m2b |= (1u << j);
        if (vc + B1 < 0.f) m2c |= (1u << j);
        if (vd + B1 < 0.f) m2d |= (1u << j);
    }
    uint8_t* b2p = (uint8_t*)(bits2 + (size_t)n * PHW + (h + 1) * PW + (w0 + 1));
    b2p[zb]      = (uint8_t)m2a;   // cell k -> byte index 8k + zb
    b2p[8 + zb]  = (uint8_t)m2b;
    b2p[16 + zb] = (uint8_t)m2c;
    b2p[24 + zb] = (uint8_t)m2d;
}

// conv2: same structure; residual from out1 (f16x4), final out f32x4 nontemporal.
template <typename InT>
__global__ __launch_bounds__(256, 4) void conv2_ep(
        const uint64_t* __restrict__ bits2, const InT* __restrict__ out1,
        const uint64_t* __restrict__ wb, const float* __restrict__ asc,
        const int* __restrict__ cint,
        const float* __restrict__ b22, const float* __restrict__ a2,
        const float* __restrict__ b23, float* __restrict__ out) {
    __shared__ int lci[CPB * 10];
    int zb = blockIdx.z;
    int ob = zb * CPB;
    for (int i = threadIdx.x; i < CPB * 10; i += 256) lci[i] = cint[ob * 10 + i];
    __syncthreads();

    int p = blockIdx.x * 256 + threadIdx.x;
    if (p >= NQUAD) return;
    int n = blockIdx.y;
    int h = p / QROW, qx = p - h * QROW;
    int w0 = qx * 4;
    int hw = h * Ww + w0;
    int rowp = (h == 0) ? 0 : (h == Hh - 1) ? 6 : 3;
    int t9a = rowp + ((qx == 0) ? 0 : 1);
    int t9m = rowp + 1;
    int t9d = rowp + ((qx == QROW - 1) ? 2 : 1);

    const uint64_t* bp = bits2 + (size_t)n * PHW + (h + 1) * PW + (w0 + 1);
    uint64_t q0[6], q1[6], q2[6];
    #pragma unroll
    for (int c = 0; c < 6; ++c) {
        q0[c] = bp[-PW - 1 + c]; q1[c] = bp[-1 + c]; q2[c] = bp[PW - 1 + c];
    }

    const InT* ip = out1 + ((size_t)n * Cc + ob) * HWp + hw;
    float* op = out + ((size_t)n * Cc + ob) * HWp + hw;

    f16x4 curh[CPB];
    f32x4 curf[CPB];
    if constexpr (sizeof(InT) == 2) {
        #pragma unroll
        for (int j = 0; j < CPB; ++j) curh[j] = *(const f16x4*)(ip + (size_t)j * HWp);
    } else {
        #pragma unroll
        for (int j = 0; j < CPB; ++j) curf[j] = *(const f32x4*)(ip + (size_t)j * HWp);
    }
    MEMFENCE();

    #pragma unroll
    for (int j = 0; j < CPB; ++j) {
        int o = ob + j;
        const uint64_t* wo = wb + o * 9;
        uint64_t t0 = wo[0], t1 = wo[1], t2 = wo[2], t3 = wo[3], t4 = wo[4],
                 t5 = wo[5], t6 = wo[6], t7 = wo[7], t8 = wo[8];
        int sa = (int)__popcll(q0[0] ^ t0) + (int)__popcll(q0[1] ^ t1) + (int)__popcll(q0[2] ^ t2)
               + (int)__popcll(q1[0] ^ t3) + (int)__popcll(q1[1] ^ t4) + (int)__popcll(q1[2] ^ t5)
               + (int)__popcll(q2[0] ^ t6) + (int)__popcll(q2[1] ^ t7) + (int)__popcll(q2[2] ^ t8);
        int sb = (int)__popcll(q0[1] ^ t0) + (int)__popcll(q0[2] ^ t1) + (int)__popcll(q0[3] ^ t2)
               + (int)__popcll(q1[1] ^ t3) + (int)__popcll(q1[2] ^ t4) + (int)__popcll(q1[3] ^ t5)
               + (int)__popcll(q2[1] ^ t6) + (int)__popcll(q2[2] ^ t7) + (int)__popcll(q2[3] ^ t8);
        int sc_ = (int)__popcll(q0[2] ^ t0) + (int)__popcll(q0[3] ^ t1) + (int)__popcll(q0[4] ^ t2)
               + (int)__popcll(q1[2] ^ t3) + (int)__popcll(q1[3] ^ t4) + (int)__popcll(q1[4] ^ t5)
               + (int)__popcll(q2[2] ^ t6) + (int)__popcll(q2[3] ^ t7) + (int)__popcll(q2[4] ^ t8);
        int sd = (int)__popcll(q0[3] ^ t0) + (int)__popcll(q0[4] ^ t1) + (int)__popcll(q0[5] ^ t2)
               + (int)__popcll(q1[3] ^ t3) + (int)__popcll(q1[4] ^ t4) + (int)__popcll(q1[5] ^ t5)
               + (int)__popcll(q2[3] ^ t6) + (int)__popcll(q2[4] ^ t7) + (int)__popcll(q2[5] ^ t8);
        int ca = lci[j * 10 + t9a];
        int cm = lci[j * 10 + t9m];
        int cd = lci[j * 10 + t9d];
        float ra, rb, rc, rd;
        if constexpr (sizeof(InT) == 2) {
            ra = (float)curh[j].x; rb = (float)curh[j].y;
            rc = (float)curh[j].z; rd = (float)curh[j].w;
        } else {
            ra = curf[j].x; rb = curf[j].y; rc = curf[j].z; rd = curf[j].w;
        }
        float scl = asc[o], B2 = b22[o], Am1 = a2[o] - 1.0f, B3 = b23[o];
        float va = fmaf(scl, (float)(ca - 2 * sa), ra);
        float vb = fmaf(scl, (float)(cm - 2 * sb), rb);
        float vc = fmaf(scl, (float)(cm - 2 * sc_), rc);
        float vd = fmaf(scl, (float)(cd - 2 * sd), rd);
        va += B2; va = fmaf(fminf(va, 0.f), Am1, va); va += B3;
        vb += B2; vb = fmaf(fminf(vb, 0.f), Am1, vb); vb += B3;
        vc += B2; vc = fmaf(fminf(vc, 0.f), Am1, vc); vc += B3;
        vd += B2; vd = fmaf(fminf(vd, 0.f), Am1, vd); vd += B3;
        f32x4 fv; fv.x = va; fv.y = vb; fv.z = vc; fv.w = vd;
        __builtin_nontemporal_store(fv, (f32x4*)(op + (size_t)j * HWp));
    }
}

extern "C" void kernel_launch(void* const* d_in, const int* in_sizes, int n_in,
                              void* d_out, int out_size, void* d_ws, size_t ws_size,
                              hipStream_t stream) {
    const float* x    = (const float*)d_in[0];
    const float* w3   = (const float*)d_in[1];
    const float* wpw  = (const float*)d_in[2];
    const float* b11  = (const float*)d_in[3];
    const float* b12  = (const float*)d_in[4];
    const float* b13  = (const float*)d_in[5];
    const float* b21  = (const float*)d_in[6];
    const float* b22  = (const float*)d_in[7];
    const float* b23  = (const float*)d_in[8];
    const float* a1   = (const float*)d_in[9];
    const float* a2   = (const float*)d_in[10];

    char* ws = (char*)d_ws;
    uint64_t* wb1   = (uint64_t*)(ws + WB1_OFF);
    uint64_t* wb2   = (uint64_t*)(ws + WB2_OFF);
    float*    asc1  = (float*)(ws + ASC1_OFF);
    float*    asc2  = (float*)(ws + ASC2_OFF);
    int*      ci1   = (int*)(ws + CI1_OFF);
    int*      ci2   = (int*)(ws + CI2_OFF);
    uint64_t* bits1 = (uint64_t*)(ws + BITS1_OFF);
    uint64_t* bits2 = (uint64_t*)(ws + BITS2_OFF);
    float*    out   = (float*)d_out;

    dim3 pgrid(15, Bn, PSP);                    // 13 quad-blocks + 2 halo; 4 ch-slices
    dim3 cgrid((NQUAD + 255) / 256, Bn, CSPC);  // 13 x 32 x 8 = 3328 blocks

    prep_weights<<<128, 64, 0, stream>>>(w3, wpw, wb1, wb2, asc1, asc2, ci1, ci2);
    pack1<<<pgrid, 256, 0, stream>>>(x, b11, bits1, bits2);

    if (ws_size >= WS_NEED) {
        __half* out1h = (__half*)(ws + OUT1H_OFF);
        conv1_ep<__half><<<cgrid, 256, 0, stream>>>(x, bits1, wb1, asc1, ci1,
                                                    b12, a1, b13, b21, out1h, bits2);
        conv2_ep<__half><<<cgrid, 256, 0, stream>>>(bits2, out1h, wb2, asc2, ci2,
                                                    b22, a2, b23, out);
    } else {
        conv1_ep<float><<<cgrid, 256, 0, stream>>>(x, bits1, wb1, asc1, ci1,
                                                   b12, a1, b13, b21, out, bits2);
        conv2_ep<float><<<cgrid, 256, 0, stream>>>(bits2, out, wb2, asc2, ci2,
                                                   b22, a2, b23, out);
    }
}